// Round 1
// baseline (114.469 us; speedup 1.0000x reference)
//
#include <hip/hip_runtime.h>

// Problem constants (from reference)
#define BB   16
#define VV   5
#define NPTS 8192
#define CCH  128
#define HH   41
#define WW   32
#define HWS  (HH * WW)      // 1312
#define BVN  (BB * VV)      // 80
#define OUTC (3 + CCH)      // 131

// ---------------------------------------------------------------------------
// Kernel 1: resolve scatter winners. numpy fancy-assignment: last i wins.
// key = (i << 11) | src  (src < 2048, i < 8192 -> 24 bits). init = -1.
// ---------------------------------------------------------------------------
__global__ void scatter_win(const int* __restrict__ i3, const int* __restrict__ i2,
                            int* __restrict__ win) {
    int t = blockIdx.x * blockDim.x + threadIdx.x;
    if (t >= BVN * NPTS) return;
    int bv = t >> 13;               // / NPTS
    int i  = t & (NPTS - 1);
    const int* p3 = i3 + (size_t)bv * (NPTS + 1);
    int cnt = p3[0];
    if (i < cnt) {
        int tgt = p3[1 + i];                          // in [0, NPTS)
        int src = i2[(size_t)bv * (NPTS + 1) + 1 + i]; // in [0, HWS)
        atomicMax(&win[bv * NPTS + tgt], (i << 11) | src);
    }
}

// ---------------------------------------------------------------------------
// Kernel 2: transpose (BV, C, HW) -> (BV, HW, C) so the gather is contiguous
// in C. HW = 41*32 and C = 128 divide 32-tiles exactly -> no bounds checks.
// ---------------------------------------------------------------------------
__global__ void transpose_feat(const float* __restrict__ in, float* __restrict__ out) {
    __shared__ float tile[32][33];
    int bv  = blockIdx.z;
    int hw0 = blockIdx.x * 32;
    int c0  = blockIdx.y * 32;
    int tx = threadIdx.x, ty = threadIdx.y;   // 32 x 8
    const float* inp  = in  + (size_t)bv * CCH * HWS;
    float*       outp = out + (size_t)bv * HWS * CCH;
#pragma unroll
    for (int j = 0; j < 4; ++j)
        tile[ty + j * 8][tx] = inp[(size_t)(c0 + ty + j * 8) * HWS + hw0 + tx];
    __syncthreads();
#pragma unroll
    for (int j = 0; j < 4; ++j)
        outp[(size_t)(hw0 + ty + j * 8) * CCH + c0 + tx] = tile[tx][ty + j * 8];
}

// ---------------------------------------------------------------------------
// Kernel 3: per point, max over views (unset view contributes 0.0 -- this is
// NOT a clamp: if all 5 views are set the max can be negative), concat xyz.
// feat_t layout (BV, HW, C): 128 threads read 512 contiguous bytes per view.
// ---------------------------------------------------------------------------
__global__ void gather_out_t(const float* __restrict__ pc, const float* __restrict__ feat_t,
                             const int* __restrict__ win, float* __restrict__ out) {
    int bp = blockIdx.x;            // b*NPTS + p
    int b  = bp >> 13;
    int p  = bp & (NPTS - 1);
    int c  = threadIdx.x;           // 0..127
    float acc = -INFINITY;
#pragma unroll
    for (int v = 0; v < VV; ++v) {
        int bv  = b * VV + v;
        int key = win[bv * NPTS + p];
        float val = 0.0f;
        if (key >= 0) {
            int src = key & 2047;
            val = feat_t[((size_t)bv * HWS + src) * CCH + c];
        }
        acc = fmaxf(acc, val);
    }
    float* orow = out + (size_t)bp * OUTC;
    orow[3 + c] = acc;
    if (c < 3) orow[c] = pc[(size_t)bp * 3 + c];
}

// Fallback gather from original (BV, C, HW) layout (if ws too small for feat_t)
__global__ void gather_out(const float* __restrict__ pc, const float* __restrict__ feat,
                           const int* __restrict__ win, float* __restrict__ out) {
    int bp = blockIdx.x;
    int b  = bp >> 13;
    int p  = bp & (NPTS - 1);
    int c  = threadIdx.x;
    float acc = -INFINITY;
#pragma unroll
    for (int v = 0; v < VV; ++v) {
        int bv  = b * VV + v;
        int key = win[bv * NPTS + p];
        float val = 0.0f;
        if (key >= 0) {
            int src = key & 2047;
            val = feat[((size_t)bv * CCH + c) * HWS + src];
        }
        acc = fmaxf(acc, val);
    }
    float* orow = out + (size_t)bp * OUTC;
    orow[3 + c] = acc;
    if (c < 3) orow[c] = pc[(size_t)bp * 3 + c];
}

extern "C" void kernel_launch(void* const* d_in, const int* in_sizes, int n_in,
                              void* d_out, int out_size, void* d_ws, size_t ws_size,
                              hipStream_t stream) {
    const float* pc   = (const float*)d_in[0];
    const float* feat = (const float*)d_in[1];
    const int*   i3   = (const int*)d_in[2];
    const int*   i2   = (const int*)d_in[3];
    float*       out  = (float*)d_out;

    const size_t win_bytes   = (size_t)BVN * NPTS * sizeof(int);          // 2.62 MB
    const size_t featT_bytes = (size_t)BVN * HWS * CCH * sizeof(float);   // 53.7 MB

    int* win = (int*)d_ws;
    // init winners to -1 (0xFF bytes)
    hipMemsetAsync(win, 0xFF, win_bytes, stream);

    scatter_win<<<(BVN * NPTS + 255) / 256, 256, 0, stream>>>(i3, i2, win);

    if (ws_size >= win_bytes + featT_bytes) {
        float* feat_t = (float*)((char*)d_ws + win_bytes);
        dim3 tg(HWS / 32, CCH / 32, BVN);
        transpose_feat<<<tg, dim3(32, 8), 0, stream>>>(feat, feat_t);
        gather_out_t<<<BB * NPTS, CCH, 0, stream>>>(pc, feat_t, win, out);
    } else {
        gather_out<<<BB * NPTS, CCH, 0, stream>>>(pc, feat, win, out);
    }
}

// Round 2
// 71.114 us; speedup vs baseline: 1.6097x; 1.6097x over previous
//
#include <hip/hip_runtime.h>

// Problem constants (from reference)
#define BB   16
#define VV   5
#define NPTS 8192
#define CCH  128
#define HH   41
#define WW   32
#define HWS  (HH * WW)      // 1312
#define BVN  (BB * VV)      // 80
#define OUTC (3 + CCH)      // 131
#define PPB  8              // points per block in gather

// ---------------------------------------------------------------------------
// Kernel 1: resolve scatter winners. numpy fancy-assignment: last i wins.
// key = (i << 11) | src  (src < 2048, i < 8192 -> 24 bits). init = -1.
// ---------------------------------------------------------------------------
__global__ void scatter_win(const int* __restrict__ i3, const int* __restrict__ i2,
                            int* __restrict__ win) {
    int t = blockIdx.x * blockDim.x + threadIdx.x;
    if (t >= BVN * NPTS) return;
    int bv = t >> 13;               // / NPTS
    int i  = t & (NPTS - 1);
    const int* p3 = i3 + (size_t)bv * (NPTS + 1);
    int cnt = p3[0];
    if (i < cnt) {
        int tgt = p3[1 + i];                           // in [0, NPTS)
        int src = i2[(size_t)bv * (NPTS + 1) + 1 + i]; // in [0, HWS)
        atomicMax(&win[bv * NPTS + tgt], (i << 11) | src);
    }
}

// ---------------------------------------------------------------------------
// Kernel 2: transpose (BV, C, HW) -> (BV, HW, C), float4 both directions.
// Tile: 32 c x 32 hw. Read float4 along HW, write float4 along C.
// LDS tile stride 37: write-phase read banks (20q+5k+h)%32 conflict-free in q.
// ---------------------------------------------------------------------------
__global__ void transpose_v4(const float* __restrict__ in, float* __restrict__ out) {
    __shared__ float tile[32][37];
    int bv  = blockIdx.z;
    int hw0 = blockIdx.x * 32;
    int c0  = blockIdx.y * 32;
    int tid = threadIdx.x;          // 256
    const float* inp  = in  + (size_t)bv * CCH * HWS;
    float*       outp = out + (size_t)bv * HWS * CCH;

    // read: ty = c row (0..31), tx = hw quad (0..7)
    {
        int ty = tid >> 3, tx = tid & 7;
        float4 v = *(const float4*)(inp + (size_t)(c0 + ty) * HWS + hw0 + 4 * tx);
        tile[ty][4 * tx + 0] = v.x;
        tile[ty][4 * tx + 1] = v.y;
        tile[ty][4 * tx + 2] = v.z;
        tile[ty][4 * tx + 3] = v.w;
    }
    __syncthreads();
    // write: h = hw (0..31), q = c quad (0..7)
    {
        int h = tid >> 3, q = tid & 7;
        float4 v;
        v.x = tile[4 * q + 0][h];
        v.y = tile[4 * q + 1][h];
        v.z = tile[4 * q + 2][h];
        v.w = tile[4 * q + 3][h];
        *(float4*)(outp + (size_t)(hw0 + h) * CCH + c0 + 4 * q) = v;
    }
}

// ---------------------------------------------------------------------------
// Kernel 3: per point, max over views (unset view contributes 0.0; NOT a
// clamp -- if all 5 views set, max can be negative). float4 gathers from
// (BV, HW, C) layout; output rows staged in LDS, copied out as aligned
// coalesced float4 (8 rows x 524B = 4192B contiguous, 16B-aligned).
// ---------------------------------------------------------------------------
__global__ void gather_out_v4(const float* __restrict__ pc, const float* __restrict__ feat_t,
                              const int* __restrict__ win, float* __restrict__ out) {
    __shared__ __align__(16) float srow[PPB * OUTC];   // 8*131 = 1048 floats
    int tid = threadIdx.x;          // 256
    int row = tid >> 5;             // 0..7
    int c4  = tid & 31;             // channel quad index
    int bp0 = blockIdx.x * PPB;
    int bp  = bp0 + row;
    int b   = bp >> 13;
    int p   = bp & (NPTS - 1);

    // prefetch all 5 winner keys (independent loads, broadcast within wave)
    int keys[VV];
#pragma unroll
    for (int v = 0; v < VV; ++v)
        keys[v] = win[(b * VV + v) * NPTS + p];

    float4 acc = make_float4(-INFINITY, -INFINITY, -INFINITY, -INFINITY);
#pragma unroll
    for (int v = 0; v < VV; ++v) {
        float4 val = make_float4(0.f, 0.f, 0.f, 0.f);
        if (keys[v] >= 0) {
            int src = keys[v] & 2047;
            val = *(const float4*)(feat_t + (((size_t)(b * VV + v) * HWS + src) << 7) + (c4 << 2));
        }
        acc.x = fmaxf(acc.x, val.x);
        acc.y = fmaxf(acc.y, val.y);
        acc.z = fmaxf(acc.z, val.z);
        acc.w = fmaxf(acc.w, val.w);
    }

    float* sr = srow + row * OUTC;
    sr[3 + 4 * c4 + 0] = acc.x;
    sr[3 + 4 * c4 + 1] = acc.y;
    sr[3 + 4 * c4 + 2] = acc.z;
    sr[3 + 4 * c4 + 3] = acc.w;
    if (c4 < 3) sr[c4] = pc[(size_t)bp * 3 + c4];
    __syncthreads();

    // coalesced aligned copy-out: 1048 floats = 262 float4
    float* obase = out + (size_t)bp0 * OUTC;
    const float4* s4 = (const float4*)srow;
    for (int i = tid; i < (PPB * OUTC) / 4; i += 256)
        *(float4*)(obase + 4 * i) = s4[i];
}

// Fallback gather from original (BV, C, HW) layout (if ws too small for feat_t)
__global__ void gather_out(const float* __restrict__ pc, const float* __restrict__ feat,
                           const int* __restrict__ win, float* __restrict__ out) {
    int bp = blockIdx.x;
    int b  = bp >> 13;
    int p  = bp & (NPTS - 1);
    int c  = threadIdx.x;
    float acc = -INFINITY;
#pragma unroll
    for (int v = 0; v < VV; ++v) {
        int bv  = b * VV + v;
        int key = win[bv * NPTS + p];
        float val = 0.0f;
        if (key >= 0) {
            int src = key & 2047;
            val = feat[((size_t)bv * CCH + c) * HWS + src];
        }
        acc = fmaxf(acc, val);
    }
    float* orow = out + (size_t)bp * OUTC;
    orow[3 + c] = acc;
    if (c < 3) orow[c] = pc[(size_t)bp * 3 + c];
}

extern "C" void kernel_launch(void* const* d_in, const int* in_sizes, int n_in,
                              void* d_out, int out_size, void* d_ws, size_t ws_size,
                              hipStream_t stream) {
    const float* pc   = (const float*)d_in[0];
    const float* feat = (const float*)d_in[1];
    const int*   i3   = (const int*)d_in[2];
    const int*   i2   = (const int*)d_in[3];
    float*       out  = (float*)d_out;

    const size_t win_bytes   = (size_t)BVN * NPTS * sizeof(int);          // 2.62 MB
    const size_t featT_bytes = (size_t)BVN * HWS * CCH * sizeof(float);   // 53.7 MB

    int* win = (int*)d_ws;
    hipMemsetAsync(win, 0xFF, win_bytes, stream);   // winners = -1

    scatter_win<<<(BVN * NPTS + 255) / 256, 256, 0, stream>>>(i3, i2, win);

    if (ws_size >= win_bytes + featT_bytes) {
        float* feat_t = (float*)((char*)d_ws + win_bytes);
        dim3 tg(HWS / 32, CCH / 32, BVN);
        transpose_v4<<<tg, 256, 0, stream>>>(feat, feat_t);
        gather_out_v4<<<(BB * NPTS) / PPB, 256, 0, stream>>>(pc, feat_t, win, out);
    } else {
        gather_out<<<BB * NPTS, CCH, 0, stream>>>(pc, feat, win, out);
    }
}